// Round 3
// baseline (452.037 us; speedup 1.0000x reference)
//
#include <hip/hip_runtime.h>
#include <stdint.h>

// Problem constants (LSTMCell_90958817394974): B=8192, I=H=1024.
// ALL device buffers are FP32 (per reference dtypes). Internal compute: bf16
// MFMA (threshold 9.125e-2 is bf16-GEMM calibrated). Output fp32.
#define BATCH 8192
#define HD    1024
#define BM    128   // batch rows per block
#define BNH   32    // h-columns per block (x4 gates = 128 N per block)
#define BK    32    // K elements per stage

typedef __bf16 bf16;
typedef __bf16 bf16x8 __attribute__((ext_vector_type(8)));
typedef __bf16 bf16x4 __attribute__((ext_vector_type(4)));
typedef float  f32x4  __attribute__((ext_vector_type(4)));

__device__ __forceinline__ float sigm(float x) {
    return 1.0f / (1.0f + __expf(-x));
}
__device__ __forceinline__ float tanh_f(float x) {
    // 1 - 2/(e^{2x}+1); saturates exactly via expf overflow/underflow
    return 1.0f - 2.0f / (__expf(2.0f * x) + 1.0f);
}
__device__ __forceinline__ bf16x4 cvt4(float4 v) {
    bf16x4 r;
    r[0] = (bf16)v.x; r[1] = (bf16)v.y; r[2] = (bf16)v.z; r[3] = (bf16)v.w;
    return r;
}

// gates[b, n] = sum_k X[b,k]*Wx[n,k] + sum_k H[b,k]*Wh[n,k], n = g*HD + h.
// Block tile: 128 batch x (32 h x 4 gates). Fused LSTM epilogue.
// fp32 global -> cvt bf16 -> LDS -> 16x16x32 bf16 MFMA, fp32 accumulate.
__global__ __launch_bounds__(256) void lstm_fused(
    const float* __restrict__ X,   // [B,1024] incoming
    const float* __restrict__ Hs,  // [B,1024] h
    const float* __restrict__ C,   // [B,1024] c
    const float* __restrict__ Wx,  // [4,1024,1024] row n contiguous in k
    const float* __restrict__ Wh,  // [4,1024,1024]
    const float* __restrict__ bx,  // [4,1024]
    const float* __restrict__ bh,  // [4,1024]
    float* __restrict__ out)       // [3,B,1024] = new_h, new_h, new_c
{
    __shared__ __align__(16) bf16 As[BM * BK];  // [128 rows][32 k] bf16, 64B rows
    __shared__ __align__(16) bf16 Bs[BM * BK];  // rows n_local: g=r>>5, h=r&31

    const int tid  = threadIdx.x;
    const int lane = tid & 63;
    const int w    = tid >> 6;          // wave 0..3
    const int m0   = blockIdx.x * BM;   // batch offset
    const int h0   = blockIdx.y * BNH;  // h offset

    f32x4 acc[2][8];
#pragma unroll
    for (int i = 0; i < 2; ++i)
#pragma unroll
        for (int j = 0; j < 8; ++j) acc[i][j] = (f32x4){0.f, 0.f, 0.f, 0.f};

    // fp32 tile = 128 rows x 32 floats (128B). Thread t, chunk j covers bytes
    // [t*16 + j*4096, +16) of the tile: row = off>>7, col(float) = (off&127)>>2.
    int arow[4], col4[4], bn[4];
#pragma unroll
    for (int j = 0; j < 4; ++j) {
        const int off = tid * 16 + j * 4096;
        arow[j] = off >> 7;
        col4[j] = (off & 127) >> 2;                       // 0,4,..,28 (float idx)
        bn[j]   = ((arow[j] >> 5) << 10) + h0 + (arow[j] & 31);  // weight row n
    }

    const int quad = lane >> 4;
    const int c16  = lane & 15;

    float4 pA[4], pB[4];
    // iteration i in [0,64): phase = i>>5 (X/Wx then H/Wh), k offset (i&31)*32
    auto loadi = [&](int i) {
        const float* Ab = (i < 32) ? X : Hs;
        const float* Wb = (i < 32) ? Wx : Wh;
        const int kin = (i & 31) << 5;
#pragma unroll
        for (int j = 0; j < 4; ++j) {
            pA[j] = *(const float4*)(Ab + (size_t)(m0 + arow[j]) * HD + kin + col4[j]);
            pB[j] = *(const float4*)(Wb + (size_t)bn[j] * HD + kin + col4[j]);
        }
    };

    loadi(0);

#pragma unroll 1
    for (int i = 0; i < 64; ++i) {
        __syncthreads();  // previous iteration's LDS reads complete
#pragma unroll
        for (int j = 0; j < 4; ++j) {
            *(bf16x4*)&As[arow[j] * BK + col4[j]] = cvt4(pA[j]);
            *(bf16x4*)&Bs[arow[j] * BK + col4[j]] = cvt4(pB[j]);
        }
        __syncthreads();  // stores visible to all waves

        if (i < 63) loadi(i + 1);  // prefetch next K-tile into registers

        bf16x8 a[2], b[8];
#pragma unroll
        for (int im = 0; im < 2; ++im) {
            const int row = w * 32 + im * 16 + c16;       // m = lane&15
            a[im] = *(const bf16x8*)((const char*)As + row * 64 + quad * 16);
        }
#pragma unroll
        for (int in = 0; in < 8; ++in) {
            const int row = in * 16 + c16;                // n = lane&15
            b[in] = *(const bf16x8*)((const char*)Bs + row * 64 + quad * 16);
        }
#pragma unroll
        for (int im = 0; im < 2; ++im)
#pragma unroll
            for (int in = 0; in < 8; ++in)
                acc[im][in] = __builtin_amdgcn_mfma_f32_16x16x32_bf16(
                    a[im], b[in], acc[im][in], 0, 0, 0);
    }

    // Epilogue. D layout (16x16x32): col = lane&15 (n), row = quad*4 + reg (m).
    // n_local = in*16 + c16 -> g = in>>1, hs = in&1: lane holds all 4 gates of
    // its (b, h) across acc registers — no cross-lane exchange needed.
    float bias[2][4];
#pragma unroll
    for (int hs = 0; hs < 2; ++hs) {
        const int h = h0 + hs * 16 + c16;
#pragma unroll
        for (int g = 0; g < 4; ++g)
            bias[hs][g] = bx[g * HD + h] + bh[g * HD + h];
    }
    const size_t BH = (size_t)BATCH * HD;
#pragma unroll
    for (int im = 0; im < 2; ++im) {
#pragma unroll
        for (int r = 0; r < 4; ++r) {
            const int m = m0 + w * 32 + im * 16 + quad * 4 + r;
#pragma unroll
            for (int hs = 0; hs < 2; ++hs) {
                const int h = h0 + hs * 16 + c16;
                const float gi = acc[im][hs + 0][r] + bias[hs][0];
                const float gf = acc[im][hs + 2][r] + bias[hs][1];
                const float gg = acc[im][hs + 4][r] + bias[hs][2];
                const float go = acc[im][hs + 6][r] + bias[hs][3];
                const float ia = sigm(gi);
                const float fa = sigm(gf);
                const float ga = tanh_f(gg);
                const float oa = sigm(go);
                const size_t idx = (size_t)m * HD + h;
                const float cv = C[idx];
                const float nc = fa * cv + ia * ga;
                const float nh = oa * tanh_f(nc);
                out[idx]          = nh;
                out[BH + idx]     = nh;
                out[2 * BH + idx] = nc;
            }
        }
    }
}

extern "C" void kernel_launch(void* const* d_in, const int* in_sizes, int n_in,
                              void* d_out, int out_size, void* d_ws, size_t ws_size,
                              hipStream_t stream) {
    const float* X  = (const float*)d_in[0];  // incoming [8192,1024]
    const float* Hs = (const float*)d_in[1];  // h        [8192,1024]
    const float* C  = (const float*)d_in[2];  // c        [8192,1024]
    const float* Wx = (const float*)d_in[3];  // [4,1024,1024]
    const float* Wh = (const float*)d_in[4];  // [4,1024,1024]
    const float* bx = (const float*)d_in[5];  // [4,1024]
    const float* bh = (const float*)d_in[6];  // [4,1024]

    dim3 grid(BATCH / BM, HD / BNH);  // 64 x 32 = 2048 blocks
    lstm_fused<<<grid, 256, 0, stream>>>(X, Hs, C, Wx, Wh, bx, bh, (float*)d_out);
}

// Round 4
// 443.246 us; speedup vs baseline: 1.0198x; 1.0198x over previous
//
#include <hip/hip_runtime.h>
#include <stdint.h>

// LSTMCell_90958817394974: B=8192, I=H=1024. All device buffers fp32.
// Strategy: prepass converts X,H,Wx,Wh -> bf16 in d_ws (48 MB); main kernel
// is the m97-style global_load_lds(16B) bf16 MFMA GEMM with fused LSTM
// epilogue (fp32 C in, fp32 out). Fallback to fp32-staging kernel if ws small.
#define BATCH 8192
#define HD    1024
#define BM    128   // batch rows per block
#define BNH   32    // h-columns per block (x4 gates = 128 N per block)
#define BK    32    // K elements per stage

typedef __bf16 bf16;
typedef __bf16 bf16x8 __attribute__((ext_vector_type(8)));
typedef __bf16 bf16x4 __attribute__((ext_vector_type(4)));
typedef float  f32x4  __attribute__((ext_vector_type(4)));

__device__ __forceinline__ float sigm(float x) {
    return 1.0f / (1.0f + __expf(-x));
}
__device__ __forceinline__ float tanh_f(float x) {
    return 1.0f - 2.0f / (__expf(2.0f * x) + 1.0f);  // saturates via expf
}
__device__ __forceinline__ bf16x4 cvt4(float4 v) {
    bf16x4 r;
    r[0] = (bf16)v.x; r[1] = (bf16)v.y; r[2] = (bf16)v.z; r[3] = (bf16)v.w;
    return r;
}
// async global->LDS, 16B/lane. HW: wave-uniform LDS base + lane*16 — our
// offsets are exactly tid*16 (+4096), so the layout matches. No padding!
__device__ __forceinline__ void async_ld16(const void* g, void* l) {
    __builtin_amdgcn_global_load_lds(
        (const __attribute__((address_space(1))) uint32_t*)g,
        (__attribute__((address_space(3))) uint32_t*)l,
        16, 0, 0);
}

// ---- prepass: fp32 -> bf16 for X, H, Wx, Wh into ws (concatenated) --------
__global__ __launch_bounds__(256) void cvt_prepass(
    const float4* __restrict__ X, const float4* __restrict__ H,
    const float4* __restrict__ Wx, const float4* __restrict__ Wh,
    bf16x4* __restrict__ ws)
{
    const size_t NX = (size_t)BATCH * HD / 4;   // 2097152 float4s per activation
    const size_t NW = (size_t)4 * HD * HD / 4;  // 1048576 float4s per weight
    const size_t total = 2 * NX + 2 * NW;       // 6291456
    const size_t stride = (size_t)gridDim.x * blockDim.x;
    for (size_t i = (size_t)blockIdx.x * blockDim.x + threadIdx.x;
         i < total; i += stride) {
        float4 v;
        if (i < NX)               v = X[i];
        else if (i < 2 * NX)      v = H[i - NX];
        else if (i < 2 * NX + NW) v = Wx[i - 2 * NX];
        else                      v = Wh[i - 2 * NX - NW];
        ws[i] = cvt4(v);
    }
}

// ---- main: gates[b,n] = X·Wx^T + H·Wh^T (n = g*HD+h), fused LSTM ----------
__global__ __launch_bounds__(256) void lstm_mfma(
    const bf16* __restrict__ Xb,   // [B,1024] bf16
    const bf16* __restrict__ Hb,   // [B,1024] bf16
    const bf16* __restrict__ Wxb,  // [4,1024,1024] bf16, row n contiguous in k
    const bf16* __restrict__ Whb,  // [4,1024,1024] bf16
    const float* __restrict__ C,   // [B,1024] fp32
    const float* __restrict__ bx,  // [4,1024] fp32
    const float* __restrict__ bh,  // [4,1024] fp32
    float* __restrict__ out)       // [3,B,1024] fp32
{
    __shared__ __align__(16) bf16 As[BM * BK];  // 8 KB, 64B rows, unpadded
    __shared__ __align__(16) bf16 Bs[BM * BK];  // rows n_local: g=r>>5, h=r&31

    const int tid  = threadIdx.x;
    const int lane = tid & 63;
    const int w    = tid >> 6;
    const int m0   = blockIdx.x * BM;
    const int h0   = blockIdx.y * BNH;

    f32x4 acc[2][8];
#pragma unroll
    for (int i = 0; i < 2; ++i)
#pragma unroll
        for (int j = 0; j < 8; ++j) acc[i][j] = (f32x4){0.f, 0.f, 0.f, 0.f};

    // 8192B tile = 256 threads x 2 insts x 16B
    const int off0 = tid * 16;
    const int off1 = off0 + 4096;
    const int ar0 = off0 >> 6, ac0 = off0 & 63;
    const int ar1 = off1 >> 6, ac1 = off1 & 63;
    const int bn0 = ((ar0 >> 5) << 10) + h0 + (ar0 & 31);
    const int bn1 = ((ar1 >> 5) << 10) + h0 + (ar1 & 31);

    const int quad = lane >> 4;
    const int c16  = lane & 15;

#pragma unroll 1
    for (int i = 0; i < 64; ++i) {
        const char* Ab = (const char*)(i < 32 ? Xb : Hb);
        const char* Wb = (const char*)(i < 32 ? Wxb : Whb);
        const int kb = (i & 31) << 6;  // byte offset within 2048B row
        async_ld16(Ab + ((size_t)(m0 + ar0) << 11) + kb + ac0, (char*)As + off0);
        async_ld16(Ab + ((size_t)(m0 + ar1) << 11) + kb + ac1, (char*)As + off1);
        async_ld16(Wb + ((size_t)bn0 << 11) + kb + ac0, (char*)Bs + off0);
        async_ld16(Wb + ((size_t)bn1 << 11) + kb + ac1, (char*)Bs + off1);
        __syncthreads();  // vmcnt(0) drain emitted before barrier

        bf16x8 a[2], b[8];
#pragma unroll
        for (int im = 0; im < 2; ++im) {
            const int row = w * 32 + im * 16 + c16;       // m = lane&15
            a[im] = *(const bf16x8*)((const char*)As + row * 64 + quad * 16);
        }
#pragma unroll
        for (int in = 0; in < 8; ++in) {
            const int row = in * 16 + c16;                // n = lane&15
            b[in] = *(const bf16x8*)((const char*)Bs + row * 64 + quad * 16);
        }
#pragma unroll
        for (int im = 0; im < 2; ++im)
#pragma unroll
            for (int in = 0; in < 8; ++in)
                acc[im][in] = __builtin_amdgcn_mfma_f32_16x16x32_bf16(
                    a[im], b[in], acc[im][in], 0, 0, 0);
        __syncthreads();  // protect LDS before next stage
    }

    // Epilogue. D: col = lane&15 (n), row = quad*4 + reg (m).
    // B row r = in*16+c16 = 32g + 16hs + c16 with in = 2g+hs — each lane holds
    // all 4 gates of its (b,h) across acc regs (verified R3, absmax 1.6e-2).
    float bias[2][4];
#pragma unroll
    for (int hs = 0; hs < 2; ++hs) {
        const int h = h0 + hs * 16 + c16;
#pragma unroll
        for (int g = 0; g < 4; ++g)
            bias[hs][g] = bx[g * HD + h] + bh[g * HD + h];
    }
    const size_t BH = (size_t)BATCH * HD;
#pragma unroll
    for (int im = 0; im < 2; ++im) {
#pragma unroll
        for (int r = 0; r < 4; ++r) {
            const int m = m0 + w * 32 + im * 16 + quad * 4 + r;
#pragma unroll
            for (int hs = 0; hs < 2; ++hs) {
                const int h = h0 + hs * 16 + c16;
                const float gi = acc[im][hs + 0][r] + bias[hs][0];
                const float gf = acc[im][hs + 2][r] + bias[hs][1];
                const float gg = acc[im][hs + 4][r] + bias[hs][2];
                const float go = acc[im][hs + 6][r] + bias[hs][3];
                const float ia = sigm(gi);
                const float fa = sigm(gf);
                const float ga = tanh_f(gg);
                const float oa = sigm(go);
                const size_t idx = (size_t)m * HD + h;
                const float cv = C[idx];
                const float nc = fa * cv + ia * ga;
                const float nh = oa * tanh_f(nc);
                out[idx]          = nh;
                out[BH + idx]     = nh;
                out[2 * BH + idx] = nc;
            }
        }
    }
}

// ---- fallback (R3, proven): fp32 loads + in-loop cvt, register staging ----
__global__ __launch_bounds__(256) void lstm_fused_f32(
    const float* __restrict__ X, const float* __restrict__ Hs,
    const float* __restrict__ C, const float* __restrict__ Wx,
    const float* __restrict__ Wh, const float* __restrict__ bx,
    const float* __restrict__ bh, float* __restrict__ out)
{
    __shared__ __align__(16) bf16 As[BM * BK];
    __shared__ __align__(16) bf16 Bs[BM * BK];
    const int tid = threadIdx.x, lane = tid & 63, w = tid >> 6;
    const int m0 = blockIdx.x * BM, h0 = blockIdx.y * BNH;
    f32x4 acc[2][8];
#pragma unroll
    for (int i = 0; i < 2; ++i)
#pragma unroll
        for (int j = 0; j < 8; ++j) acc[i][j] = (f32x4){0.f, 0.f, 0.f, 0.f};
    int arow[4], col4[4], bn[4];
#pragma unroll
    for (int j = 0; j < 4; ++j) {
        const int off = tid * 16 + j * 4096;
        arow[j] = off >> 7;
        col4[j] = (off & 127) >> 2;
        bn[j]   = ((arow[j] >> 5) << 10) + h0 + (arow[j] & 31);
    }
    const int quad = lane >> 4, c16 = lane & 15;
    float4 pA[4], pB[4];
    auto loadi = [&](int i) {
        const float* Ab = (i < 32) ? X : Hs;
        const float* Wb = (i < 32) ? Wx : Wh;
        const int kin = (i & 31) << 5;
#pragma unroll
        for (int j = 0; j < 4; ++j) {
            pA[j] = *(const float4*)(Ab + (size_t)(m0 + arow[j]) * HD + kin + col4[j]);
            pB[j] = *(const float4*)(Wb + (size_t)bn[j] * HD + kin + col4[j]);
        }
    };
    loadi(0);
#pragma unroll 1
    for (int i = 0; i < 64; ++i) {
        __syncthreads();
#pragma unroll
        for (int j = 0; j < 4; ++j) {
            *(bf16x4*)&As[arow[j] * BK + col4[j]] = cvt4(pA[j]);
            *(bf16x4*)&Bs[arow[j] * BK + col4[j]] = cvt4(pB[j]);
        }
        __syncthreads();
        if (i < 63) loadi(i + 1);
        bf16x8 a[2], b[8];
#pragma unroll
        for (int im = 0; im < 2; ++im)
            a[im] = *(const bf16x8*)((const char*)As + (w * 32 + im * 16 + c16) * 64 + quad * 16);
#pragma unroll
        for (int in = 0; in < 8; ++in)
            b[in] = *(const bf16x8*)((const char*)Bs + (in * 16 + c16) * 64 + quad * 16);
#pragma unroll
        for (int im = 0; im < 2; ++im)
#pragma unroll
            for (int in = 0; in < 8; ++in)
                acc[im][in] = __builtin_amdgcn_mfma_f32_16x16x32_bf16(
                    a[im], b[in], acc[im][in], 0, 0, 0);
    }
    float bias[2][4];
#pragma unroll
    for (int hs = 0; hs < 2; ++hs) {
        const int h = h0 + hs * 16 + c16;
#pragma unroll
        for (int g = 0; g < 4; ++g) bias[hs][g] = bx[g * HD + h] + bh[g * HD + h];
    }
    const size_t BH = (size_t)BATCH * HD;
#pragma unroll
    for (int im = 0; im < 2; ++im)
#pragma unroll
        for (int r = 0; r < 4; ++r) {
            const int m = m0 + w * 32 + im * 16 + quad * 4 + r;
#pragma unroll
            for (int hs = 0; hs < 2; ++hs) {
                const int h = h0 + hs * 16 + c16;
                const float gi = acc[im][hs + 0][r] + bias[hs][0];
                const float gf = acc[im][hs + 2][r] + bias[hs][1];
                const float gg = acc[im][hs + 4][r] + bias[hs][2];
                const float go = acc[im][hs + 6][r] + bias[hs][3];
                const float ia = sigm(gi), fa = sigm(gf);
                const float ga = tanh_f(gg), oa = sigm(go);
                const size_t idx = (size_t)m * HD + h;
                const float nc = fa * C[idx] + ia * ga;
                const float nh = oa * tanh_f(nc);
                out[idx] = nh; out[BH + idx] = nh; out[2 * BH + idx] = nc;
            }
        }
}

extern "C" void kernel_launch(void* const* d_in, const int* in_sizes, int n_in,
                              void* d_out, int out_size, void* d_ws, size_t ws_size,
                              hipStream_t stream) {
    const float* X  = (const float*)d_in[0];
    const float* Hs = (const float*)d_in[1];
    const float* C  = (const float*)d_in[2];
    const float* Wx = (const float*)d_in[3];
    const float* Wh = (const float*)d_in[4];
    const float* bx = (const float*)d_in[5];
    const float* bh = (const float*)d_in[6];
    float* out = (float*)d_out;

    dim3 grid(BATCH / BM, HD / BNH);  // 64 x 32 = 2048 blocks
    const size_t need = 48ull << 20;  // Xb+Hb (32MB) + Wxb+Whb (16MB)
    if (ws_size >= need) {
        bf16* Xb  = (bf16*)d_ws;
        bf16* Hb  = Xb + (size_t)BATCH * HD;
        bf16* Wxb = Hb + (size_t)BATCH * HD;
        bf16* Whb = Wxb + (size_t)4 * HD * HD;
        cvt_prepass<<<4096, 256, 0, stream>>>(
            (const float4*)X, (const float4*)Hs,
            (const float4*)Wx, (const float4*)Wh, (bf16x4*)d_ws);
        lstm_mfma<<<grid, 256, 0, stream>>>(Xb, Hb, Wxb, Whb, C, bx, bh, out);
    } else {
        lstm_fused_f32<<<grid, 256, 0, stream>>>(X, Hs, C, Wx, Wh, bx, bh, out);
    }
}

// Round 5
// 372.875 us; speedup vs baseline: 1.2123x; 1.1887x over previous
//
#include <hip/hip_runtime.h>
#include <stdint.h>

// LSTMCell_90958817394974: B=8192, I=H=1024. All device buffers fp32.
// Prepass converts X,H,Wx,Wh -> bf16 in d_ws; main kernel = m97-style
// global_load_lds(16B) bf16 MFMA GEMM, m97-exact 64x64 wave tiles
// (8 ds_read_b128 : 16 MFMA), gate-interleaved B-row mapping so each lane
// holds all 4 gates of its (b,h). Fused LSTM epilogue, fp32 out.
#define BATCH 8192
#define HD    1024
#define BM    128   // batch rows per block
#define BNH   32    // h-columns per block (x4 gates = 128 N per block)
#define BK    32    // K elements per stage

typedef __bf16 bf16;
typedef __bf16 bf16x8 __attribute__((ext_vector_type(8)));
typedef __bf16 bf16x4 __attribute__((ext_vector_type(4)));
typedef float  f32x4  __attribute__((ext_vector_type(4)));

__device__ __forceinline__ float sigm(float x) {
    return 1.0f / (1.0f + __expf(-x));
}
__device__ __forceinline__ float tanh_f(float x) {
    return 1.0f - 2.0f / (__expf(2.0f * x) + 1.0f);  // saturates via expf
}
__device__ __forceinline__ bf16x4 cvt4(float4 v) {
    bf16x4 r;
    r[0] = (bf16)v.x; r[1] = (bf16)v.y; r[2] = (bf16)v.z; r[3] = (bf16)v.w;
    return r;
}
// async global->LDS, 16B/lane; LDS dest = wave-uniform base + lane*16.
__device__ __forceinline__ void async_ld16(const void* g, void* l) {
    __builtin_amdgcn_global_load_lds(
        (const __attribute__((address_space(1))) uint32_t*)g,
        (__attribute__((address_space(3))) uint32_t*)l,
        16, 0, 0);
}

// ---- prepass: fp32 -> bf16 for X, H, Wx, Wh into ws (concatenated) --------
__global__ __launch_bounds__(256) void cvt_prepass(
    const float4* __restrict__ X, const float4* __restrict__ H,
    const float4* __restrict__ Wx, const float4* __restrict__ Wh,
    bf16x4* __restrict__ ws)
{
    const size_t NX = (size_t)BATCH * HD / 4;
    const size_t NW = (size_t)4 * HD * HD / 4;
    const size_t total = 2 * NX + 2 * NW;
    const size_t stride = (size_t)gridDim.x * blockDim.x;
    for (size_t i = (size_t)blockIdx.x * blockDim.x + threadIdx.x;
         i < total; i += stride) {
        float4 v;
        if (i < NX)               v = X[i];
        else if (i < 2 * NX)      v = H[i - NX];
        else if (i < 2 * NX + NW) v = Wx[i - 2 * NX];
        else                      v = Wh[i - 2 * NX - NW];
        ws[i] = cvt4(v);
    }
}

// ---- main: gates[b,n] = X·Wx^T + H·Wh^T, fused LSTM -----------------------
// LDS B row r -> weight row n = ((r>>4)&3)*1024 + h0 + (r>>6)*16 + (r&15).
// Wave w = (wm = w>>1)*64 batch-rows, (wn = w&1): b-frag 'in' = gate in at
// h-half wn. So acc[im][g] per lane = gate g of (b, h0 + wn*16 + c16).
__global__ __launch_bounds__(256) void lstm_mfma(
    const bf16* __restrict__ Xb,   // [B,1024] bf16
    const bf16* __restrict__ Hb,   // [B,1024] bf16
    const bf16* __restrict__ Wxb,  // [4,1024,1024] bf16, row n contig in k
    const bf16* __restrict__ Whb,  // [4,1024,1024] bf16
    const float* __restrict__ C,   // [B,1024] fp32
    const float* __restrict__ bx,  // [4,1024] fp32
    const float* __restrict__ bh,  // [4,1024] fp32
    float* __restrict__ out)       // [3,B,1024] fp32
{
    __shared__ __align__(16) bf16 As[BM * BK];  // 8 KB, 64B rows, unpadded
    __shared__ __align__(16) bf16 Bs[BM * BK];

    const int tid  = threadIdx.x;
    const int lane = tid & 63;
    const int w    = tid >> 6;
    const int wm   = w >> 1;            // batch half (0/1)
    const int wn   = w & 1;             // h half (0/1)
    const int m0   = blockIdx.x * BM;
    const int h0   = blockIdx.y * BNH;

    f32x4 acc[4][4];
#pragma unroll
    for (int i = 0; i < 4; ++i)
#pragma unroll
        for (int j = 0; j < 4; ++j) acc[i][j] = (f32x4){0.f, 0.f, 0.f, 0.f};

    // Staging: 8192B tile = 256 threads x 2 insts x 16B.
    const int off0 = tid * 16;          // rows 0..63
    const int off1 = off0 + 4096;       // rows 64..127
    const int ar0 = off0 >> 6, ac0 = off0 & 63;
    const int ar1 = off1 >> 6, ac1 = off1 & 63;
    // B-row r -> n = gate*1024 + h0 + half*16 + (r&15)
    const int bn0 = (((ar0 >> 4) & 3) << 10) + h0 + ((ar0 >> 6) << 4) + (ar0 & 15);
    const int bn1 = (((ar1 >> 4) & 3) << 10) + h0 + ((ar1 >> 6) << 4) + (ar1 & 15);

    const int quad = lane >> 4;
    const int c16  = lane & 15;

#pragma unroll 1
    for (int phase = 0; phase < 2; ++phase) {
        const char* Ab = (const char*)(phase == 0 ? Xb : Hb);
        const char* Wb = (const char*)(phase == 0 ? Wxb : Whb);
#pragma unroll 1
        for (int kk = 0; kk < 32; ++kk) {
            const int kb = kk << 6;  // byte offset within 2048B row
            async_ld16(Ab + ((size_t)(m0 + ar0) << 11) + kb + ac0, (char*)As + off0);
            async_ld16(Ab + ((size_t)(m0 + ar1) << 11) + kb + ac1, (char*)As + off1);
            async_ld16(Wb + ((size_t)bn0 << 11) + kb + ac0, (char*)Bs + off0);
            async_ld16(Wb + ((size_t)bn1 << 11) + kb + ac1, (char*)Bs + off1);
            __syncthreads();  // vmcnt(0) drain emitted before barrier

            bf16x8 a[4], b[4];
#pragma unroll
            for (int im = 0; im < 4; ++im) {
                const int row = wm * 64 + im * 16 + c16;      // m row
                a[im] = *(const bf16x8*)((const char*)As + row * 64 + quad * 16);
            }
#pragma unroll
            for (int in = 0; in < 4; ++in) {
                const int row = wn * 64 + in * 16 + c16;      // gate in, half wn
                b[in] = *(const bf16x8*)((const char*)Bs + row * 64 + quad * 16);
            }
#pragma unroll
            for (int im = 0; im < 4; ++im)
#pragma unroll
                for (int in = 0; in < 4; ++in)
                    acc[im][in] = __builtin_amdgcn_mfma_f32_16x16x32_bf16(
                        a[im], b[in], acc[im][in], 0, 0, 0);
            __syncthreads();  // protect LDS before next stage
        }
    }

    // Epilogue. D layout: col = lane&15, row = quad*4 + reg.
    // acc[im][g][reg] = gate g of batch row m0+wm*64+im*16+quad*4+reg,
    // h = h0 + wn*16 + c16 (one h per lane, all 4 gates local).
    const int h = h0 + wn * 16 + c16;
    float bias[4];
#pragma unroll
    for (int g = 0; g < 4; ++g)
        bias[g] = bx[g * HD + h] + bh[g * HD + h];

    const size_t BH = (size_t)BATCH * HD;
#pragma unroll
    for (int im = 0; im < 4; ++im) {
#pragma unroll
        for (int r = 0; r < 4; ++r) {
            const int m = m0 + wm * 64 + im * 16 + quad * 4 + r;
            const float gi = acc[im][0][r] + bias[0];
            const float gf = acc[im][1][r] + bias[1];
            const float gg = acc[im][2][r] + bias[2];
            const float go = acc[im][3][r] + bias[3];
            const float ia = sigm(gi);
            const float fa = sigm(gf);
            const float ga = tanh_f(gg);
            const float oa = sigm(go);
            const size_t idx = (size_t)m * HD + h;
            const float nc = fmaf(fa, C[idx], ia * ga);
            const float nh = oa * tanh_f(nc);
            out[idx]          = nh;
            out[BH + idx]     = nh;
            out[2 * BH + idx] = nc;
        }
    }
}

// ---- fallback (R3, proven): fp32 loads + in-loop cvt, register staging ----
__global__ __launch_bounds__(256) void lstm_fused_f32(
    const float* __restrict__ X, const float* __restrict__ Hs,
    const float* __restrict__ C, const float* __restrict__ Wx,
    const float* __restrict__ Wh, const float* __restrict__ bx,
    const float* __restrict__ bh, float* __restrict__ out)
{
    __shared__ __align__(16) bf16 As[BM * BK];
    __shared__ __align__(16) bf16 Bs[BM * BK];
    const int tid = threadIdx.x, lane = tid & 63, w = tid >> 6;
    const int m0 = blockIdx.x * BM, h0 = blockIdx.y * BNH;
    f32x4 acc[2][8];
#pragma unroll
    for (int i = 0; i < 2; ++i)
#pragma unroll
        for (int j = 0; j < 8; ++j) acc[i][j] = (f32x4){0.f, 0.f, 0.f, 0.f};
    int arow[4], col4[4], bn[4];
#pragma unroll
    for (int j = 0; j < 4; ++j) {
        const int off = tid * 16 + j * 4096;
        arow[j] = off >> 7;
        col4[j] = (off & 127) >> 2;
        bn[j]   = ((arow[j] >> 5) << 10) + h0 + (arow[j] & 31);
    }
    const int quad = lane >> 4, c16 = lane & 15;
    float4 pA[4], pB[4];
    auto loadi = [&](int i) {
        const float* Ab = (i < 32) ? X : Hs;
        const float* Wb = (i < 32) ? Wx : Wh;
        const int kin = (i & 31) << 5;
#pragma unroll
        for (int j = 0; j < 4; ++j) {
            pA[j] = *(const float4*)(Ab + (size_t)(m0 + arow[j]) * HD + kin + col4[j]);
            pB[j] = *(const float4*)(Wb + (size_t)bn[j] * HD + kin + col4[j]);
        }
    };
    loadi(0);
#pragma unroll 1
    for (int i = 0; i < 64; ++i) {
        __syncthreads();
#pragma unroll
        for (int j = 0; j < 4; ++j) {
            *(bf16x4*)&As[arow[j] * BK + col4[j]] = cvt4(pA[j]);
            *(bf16x4*)&Bs[arow[j] * BK + col4[j]] = cvt4(pB[j]);
        }
        __syncthreads();
        if (i < 63) loadi(i + 1);
        bf16x8 a[2], b[8];
#pragma unroll
        for (int im = 0; im < 2; ++im)
            a[im] = *(const bf16x8*)((const char*)As + (w * 32 + im * 16 + c16) * 64 + quad * 16);
#pragma unroll
        for (int in = 0; in < 8; ++in)
            b[in] = *(const bf16x8*)((const char*)Bs + (in * 16 + c16) * 64 + quad * 16);
#pragma unroll
        for (int im = 0; im < 2; ++im)
#pragma unroll
            for (int in = 0; in < 8; ++in)
                acc[im][in] = __builtin_amdgcn_mfma_f32_16x16x32_bf16(
                    a[im], b[in], acc[im][in], 0, 0, 0);
    }
    float bias[2][4];
#pragma unroll
    for (int hs = 0; hs < 2; ++hs) {
        const int h = h0 + hs * 16 + c16;
#pragma unroll
        for (int g = 0; g < 4; ++g) bias[hs][g] = bx[g * HD + h] + bh[g * HD + h];
    }
    const size_t BH = (size_t)BATCH * HD;
#pragma unroll
    for (int im = 0; im < 2; ++im)
#pragma unroll
        for (int r = 0; r < 4; ++r) {
            const int m = m0 + w * 32 + im * 16 + quad * 4 + r;
#pragma unroll
            for (int hs = 0; hs < 2; ++hs) {
                const int h = h0 + hs * 16 + c16;
                const float gi = acc[im][hs + 0][r] + bias[hs][0];
                const float gf = acc[im][hs + 2][r] + bias[hs][1];
                const float gg = acc[im][hs + 4][r] + bias[hs][2];
                const float go = acc[im][hs + 6][r] + bias[hs][3];
                const float ia = sigm(gi), fa = sigm(gf);
                const float ga = tanh_f(gg), oa = sigm(go);
                const size_t idx = (size_t)m * HD + h;
                const float nc = fa * C[idx] + ia * ga;
                const float nh = oa * tanh_f(nc);
                out[idx] = nh; out[BH + idx] = nh; out[2 * BH + idx] = nc;
            }
        }
}

extern "C" void kernel_launch(void* const* d_in, const int* in_sizes, int n_in,
                              void* d_out, int out_size, void* d_ws, size_t ws_size,
                              hipStream_t stream) {
    const float* X  = (const float*)d_in[0];
    const float* Hs = (const float*)d_in[1];
    const float* C  = (const float*)d_in[2];
    const float* Wx = (const float*)d_in[3];
    const float* Wh = (const float*)d_in[4];
    const float* bx = (const float*)d_in[5];
    const float* bh = (const float*)d_in[6];
    float* out = (float*)d_out;

    dim3 grid(BATCH / BM, HD / BNH);  // 64 x 32 = 2048 blocks
    const size_t need = 48ull << 20;  // Xb+Hb (32MB) + Wxb+Whb (16MB)
    if (ws_size >= need) {
        bf16* Xb  = (bf16*)d_ws;
        bf16* Hb  = Xb + (size_t)BATCH * HD;
        bf16* Wxb = Hb + (size_t)BATCH * HD;
        bf16* Whb = Wxb + (size_t)4 * HD * HD;
        cvt_prepass<<<4096, 256, 0, stream>>>(
            (const float4*)X, (const float4*)Hs,
            (const float4*)Wx, (const float4*)Wh, (bf16x4*)d_ws);
        lstm_mfma<<<grid, 256, 0, stream>>>(Xb, Hb, Wxb, Whb, C, bx, bh, out);
    } else {
        lstm_fused_f32<<<grid, 256, 0, stream>>>(X, Hs, C, Wx, Wh, bx, bh, out);
    }
}